// Round 1
// 454.230 us; speedup vs baseline: 1.0044x; 1.0044x over previous
//
#include <hip/hip_runtime.h>

#define NN 100000
#define NE 1600000
#define D 128
#define LEAKY 0.01f
#define BNEPS 1e-5f

#define G 256        // sort groups (workgroups)
#define CHUNK 6250   // NE / G exactly
#define B 782        // ceil(NN/128) dst-buckets
#define BSHIFT 7
#define BMASK 127
#define NXCD 8       // MI355X: 8 XCDs, each with private (non-cross-coherent) L2

typedef short v8s __attribute__((ext_vector_type(8)));
typedef float v4f __attribute__((ext_vector_type(4)));

// round-to-nearest-even f32 -> bf16 (returns low 16 bits)
__device__ __forceinline__ unsigned f2bf(float f) {
    unsigned u = __float_as_uint(f);
    return (u + 0x7fffu + ((u >> 16) & 1u)) >> 16;
}
__device__ __forceinline__ float bf2f(unsigned h) {
    return __uint_as_float(h << 16);
}

// physical XCD id (0..7) — HW-verified readable on gfx950 via HW_REG_XCC_ID.
// MUST be the hardware id (not blockIdx%8): two blocks on different XCDs
// writing the same partial with L2-local atomics would race non-coherently.
__device__ __forceinline__ int xcc_id() {
    int x;
    asm volatile("s_getreg_b32 %0, hwreg(HW_REG_XCC_ID)" : "=s"(x));
    return x & (NXCD - 1);
}

// ---------------- counting sort by dst bucket + fused out-degree ----------------
// Round-8 evidence: agent-scope atomicAdd(&deg[src]) bypasses the per-XCD L2
// (56 MB WRITE_SIZE = 1.6M x ~32B memory-side transactions, 70 us latency-bound
// at 9% occupancy). Fix: per-XCD privatized partials + WORKGROUP-scope atomics
// that execute in the local L2 (400 KB partial = L2-resident), reduced later
// in conv_kernel. Block size 1024: grid is pinned at G=256 (1 block/CU), so
// bigger blocks are the only occupancy lever (4 -> 16 waves/CU).

__global__ __launch_bounds__(1024) void hist_kernel(const int* __restrict__ src,
                                                    const int* __restrict__ dst,
                                                    int* __restrict__ degP,
                                                    int* __restrict__ hist) {
    __shared__ int h[B];
    for (int i = threadIdx.x; i < B; i += 1024) h[i] = 0;
    __syncthreads();
    int g = blockIdx.x;
    int* dp0 = (int*)(degP) + (size_t)xcc_id() * NN;
    const int* dp = dst + g * CHUNK;
    const int* sp = src + g * CHUNK;
    for (int k = threadIdx.x; k < CHUNK; k += 1024) {
        atomicAdd(&h[dp[k] >> BSHIFT], 1);
        // L2-local atomic: no sc1, stays in this XCD's L2
        __hip_atomic_fetch_add(&dp0[sp[k]], 1, __ATOMIC_RELAXED,
                               __HIP_MEMORY_SCOPE_WORKGROUP);
    }
    __syncthreads();
    for (int i = threadIdx.x; i < B; i += 1024) hist[i * G + g] = h[i];
}

__global__ void scanA(const int* __restrict__ a, int* __restrict__ bsum) {
    __shared__ int sm[256];
    int t = threadIdx.x;
    sm[t] = a[blockIdx.x * 256 + t];
    __syncthreads();
    for (int s = 128; s > 0; s >>= 1) {
        if (t < s) sm[t] += sm[t + s];
        __syncthreads();
    }
    if (t == 0) bsum[blockIdx.x] = sm[0];
}

__global__ void scanB(const int* __restrict__ bsum, int* __restrict__ boffs) {
    int lane = threadIdx.x;
    int run = 0;
    for (int base = 0; base < B; base += 64) {
        int i = base + lane;
        int v = (i < B) ? bsum[i] : 0;
        int orig = v;
        for (int off = 1; off < 64; off <<= 1) {
            int t = __shfl_up(v, off);
            if (lane >= off) v += t;
        }
        if (i < B) boffs[i] = run + v - orig;   // exclusive
        run += __shfl(v, 63);
    }
}

__global__ void scanC(const int* __restrict__ a, const int* __restrict__ boffs,
                      int* __restrict__ offs) {
    __shared__ int sm[256];
    int t = threadIdx.x;
    int i = blockIdx.x * 256 + t;
    int v = a[i];
    sm[t] = v;
    __syncthreads();
    for (int off = 1; off < 256; off <<= 1) {
        int x = (t >= off) ? sm[t - off] : 0;
        __syncthreads();
        sm[t] += x;
        __syncthreads();
    }
    offs[i] = boffs[blockIdx.x] + sm[t] - v;    // exclusive
}

__global__ __launch_bounds__(1024) void sort_kernel(const int* __restrict__ src,
                                                    const int* __restrict__ dst,
                                                    const int* __restrict__ offs,
                                                    unsigned* __restrict__ ebuf) {
    __shared__ int cur[B];
    int g = blockIdx.x;
    for (int i = threadIdx.x; i < B; i += 1024) cur[i] = offs[i * G + g];
    __syncthreads();
    const int* sp = src + g * CHUNK;
    const int* dp = dst + g * CHUNK;
    for (int k = threadIdx.x; k < CHUNK; k += 1024) {
        int d = dp[k], s = sp[k];
        int pos = atomicAdd(&cur[d >> BSHIFT], 1);
        ebuf[pos] = ((unsigned)(d & BMASK) << 17) | (unsigned)s;   // src < 2^17
    }
}

// ---------------- norm_s + x*norm_s -> bf16 gather source (fused) ----------------
// Also reduces the 8 per-XCD degree partials (one row per wave -> the 8 loads
// are wave-broadcast, L2-hit; noise-level cost vs the 51 MB x stream).

__global__ __launch_bounds__(256) void conv_kernel(const float* __restrict__ x,
                                                   const int* __restrict__ degP,
                                                   float* __restrict__ norm_s,
                                                   unsigned* __restrict__ hb) {
    int t = blockIdx.x * 256 + threadIdx.x;     // one u32 pair per thread
    if (t >= NN * 64) return;
    int row = t >> 6;
    int dsum = 0;
    #pragma unroll
    for (int p = 0; p < NXCD; ++p) dsum += degP[(size_t)p * NN + row];
    float ns = rsqrtf((float)(dsum + 1));       // +1 = self-loop
    if ((t & 63) == 0) norm_s[row] = ns;
    float2 v = ((const float2*)x)[t];
    hb[t] = f2bf(v.x * ns) | (f2bf(v.y * ns) << 16);
}

// ---------------- per-bucket local sort: bucket order -> per-node CSR ----------

__global__ __launch_bounds__(256) void local_sort(
    const int* __restrict__ offs, unsigned* __restrict__ ebuf,
    int* __restrict__ row, float* __restrict__ norm_d)
{
    __shared__ int cnt[128];
    __shared__ int sc[128];
    const int b = blockIdx.x;
    const int t = threadIdx.x;
    const int s = offs[b * G];
    const int e = (b == B - 1) ? NE : offs[(b + 1) * G];
    if (t < 128) cnt[t] = 0;
    __syncthreads();

    unsigned ent[16];   // 16*256 = 4096 capacity; bucket mean 2048, sd ~45
    int nent = 0;
    for (int k = s + t; k < e && nent < 16; k += 256) {
        unsigned u = ebuf[k];
        ent[nent++] = u;
        atomicAdd(&cnt[u >> 17], 1);
    }
    __syncthreads();

    if (t < 128) sc[t] = cnt[t];
    __syncthreads();
    for (int off = 1; off < 128; off <<= 1) {
        int v = 0;
        if (t < 128 && t >= off) v = sc[t - off];
        __syncthreads();
        if (t < 128) sc[t] += v;
        __syncthreads();
    }
    if (t < 128) {
        int st = s + sc[t] - cnt[t];   // exclusive start
        int node = b * 128 + t;
        if (node < NN) {
            row[node] = st;
            norm_d[node] = rsqrtf((float)(cnt[t] + 1));
        }
        cnt[t] = st;                   // becomes cursor
    }
    if (b == B - 1 && t == 0) row[NN] = NE;
    __syncthreads();

    for (int i = 0; i < nent; ++i) {
        unsigned u = ent[i];
        int pos = atomicAdd(&cnt[u >> 17], 1);
        ebuf[pos] = u & 0x1FFFFu;      // strip bucket bits -> plain src id
    }
}

// ---------------- CSR gather-aggregate over bf16 rows, fp32 accumulate --------
// One wave per node, 8 gathers in flight (proven best: round 6). Output split
// bf16 hi/lo planes for the MFMA GEMM.

__global__ __launch_bounds__(256) void csr_agg(
    const int* __restrict__ row, const int* __restrict__ csr,
    const unsigned* __restrict__ hp,
    unsigned* __restrict__ Ahi, unsigned* __restrict__ Alo)
{
    int i = blockIdx.x * 4 + (threadIdx.x >> 6);
    if (i >= NN) return;
    int lane = threadIdx.x & 63;

    float2 acc;
    {
        unsigned u = hp[(size_t)i * 64 + lane];
        acc.x = __uint_as_float(u << 16);
        acc.y = __uint_as_float(u & 0xffff0000u);
    }

    int start = row[i], end = row[i + 1];
    for (int base = start; base < end; base += 64) {
        int n = end - base; if (n > 64) n = 64;
        int sv = csr[base + (lane < n ? lane : n - 1)];
        int j = 0;
        for (; j + 8 <= n; j += 8) {
            int ss[8]; unsigned uu[8];
            #pragma unroll
            for (int t = 0; t < 8; ++t) ss[t] = __shfl(sv, j + t);
            #pragma unroll
            for (int t = 0; t < 8; ++t) uu[t] = hp[(size_t)ss[t] * 64 + lane];
            #pragma unroll
            for (int t = 0; t < 8; ++t) {
                acc.x += __uint_as_float(uu[t] << 16);
                acc.y += __uint_as_float(uu[t] & 0xffff0000u);
            }
        }
        for (; j < n; ++j) {
            int s = __shfl(sv, j);
            unsigned u = hp[(size_t)s * 64 + lane];
            acc.x += __uint_as_float(u << 16);
            acc.y += __uint_as_float(u & 0xffff0000u);
        }
    }
    unsigned hx = f2bf(acc.x), hy = f2bf(acc.y);
    float lx = acc.x - bf2f(hx), ly = acc.y - bf2f(hy);
    Ahi[(size_t)i * 64 + lane] = hx | (hy << 16);
    Alo[(size_t)i * 64 + lane] = f2bf(lx) | (f2bf(ly) << 16);
}

// ---------------- MFMA GEMM, split-precision bf16 (3-mfma ~ fp32 accuracy) -----

template<bool LAYER0>
__global__ __launch_bounds__(256) void gemm_kernel(
    const unsigned* __restrict__ Ahi_g, const unsigned* __restrict__ Alo_g,
    const float* __restrict__ W, const float* __restrict__ bias,
    const float* __restrict__ norm_s, const float* __restrict__ norm_d,
    const float* __restrict__ gamma, const float* __restrict__ beta,
    const float* __restrict__ rmean, const float* __restrict__ rvar,
    float* __restrict__ outf, unsigned short* __restrict__ outb)
{
    __shared__ unsigned lhi[64 * 68];   // 64 rows x 136 bf16 (pad 8)
    __shared__ unsigned llo[64 * 68];

    const int w    = threadIdx.x >> 6;
    const int lane = threadIdx.x & 63;
    const int quad = lane >> 4;
    const int l16  = lane & 15;

    // ---- B fragments (hi/lo) for this wave's 2 col-tiles, all K ----
    v8s Bhi[2][4], Blo[2][4];
    int col[2];
    #pragma unroll
    for (int ct = 0; ct < 2; ++ct) {
        col[ct] = 32 * w + 16 * ct + l16;
        #pragma unroll
        for (int q = 0; q < 4; ++q) {
            int kb = 32 * q + quad * 8;
            v8s hi8, lo8;
            #pragma unroll
            for (int kk = 0; kk < 8; ++kk) {
                float wv = W[(kb + kk) * D + col[ct]];
                unsigned h = f2bf(wv);
                hi8[kk] = (short)h;
                lo8[kk] = (short)f2bf(wv - bf2f(h));
            }
            Bhi[ct][q] = hi8;
            Blo[ct][q] = lo8;
        }
    }

    float bcol[2], s[2] = {0.f, 0.f}, sh[2] = {0.f, 0.f};
    #pragma unroll
    for (int ct = 0; ct < 2; ++ct) {
        bcol[ct] = bias[col[ct]];
        if (LAYER0) {
            s[ct]  = gamma[col[ct]] * rsqrtf(rvar[col[ct]] + BNEPS);
            sh[ct] = beta[col[ct]] - rmean[col[ct]] * s[ct];
        }
    }

    for (int row0 = blockIdx.x * 64; row0 < NN; row0 += gridDim.x * 64) {
        __syncthreads();
        for (int idx = threadIdx.x; idx < 64 * 64; idx += 256) {
            int r = idx >> 6, cp = idx & 63;
            int rw = row0 + r;
            unsigned vh = 0, vl = 0;
            if (rw < NN) {
                vh = Ahi_g[(size_t)rw * 64 + cp];
                vl = Alo_g[(size_t)rw * 64 + cp];
            }
            lhi[r * 68 + cp] = vh;
            llo[r * 68 + cp] = vl;
        }
        __syncthreads();

        #pragma unroll
        for (int rt = 0; rt < 4; ++rt) {
            v4f acc0 = {0.f, 0.f, 0.f, 0.f};
            v4f acc1 = {0.f, 0.f, 0.f, 0.f};
            #pragma unroll
            for (int q = 0; q < 4; ++q) {
                const unsigned short* ph = (const unsigned short*)lhi
                    + (rt * 16 + l16) * 136 + q * 32 + quad * 8;
                const unsigned short* pl = (const unsigned short*)llo
                    + (rt * 16 + l16) * 136 + q * 32 + quad * 8;
                v8s ahi = *(const v8s*)ph;
                v8s alo = *(const v8s*)pl;
                acc0 = __builtin_amdgcn_mfma_f32_16x16x32_bf16(ahi, Bhi[0][q], acc0, 0, 0, 0);
                acc0 = __builtin_amdgcn_mfma_f32_16x16x32_bf16(alo, Bhi[0][q], acc0, 0, 0, 0);
                acc0 = __builtin_amdgcn_mfma_f32_16x16x32_bf16(ahi, Blo[0][q], acc0, 0, 0, 0);
                acc1 = __builtin_amdgcn_mfma_f32_16x16x32_bf16(ahi, Bhi[1][q], acc1, 0, 0, 0);
                acc1 = __builtin_amdgcn_mfma_f32_16x16x32_bf16(alo, Bhi[1][q], acc1, 0, 0, 0);
                acc1 = __builtin_amdgcn_mfma_f32_16x16x32_bf16(ahi, Blo[1][q], acc1, 0, 0, 0);
            }
            #pragma unroll
            for (int r = 0; r < 4; ++r) {
                int rw = row0 + rt * 16 + quad * 4 + r;
                if (rw >= NN) continue;
                float nd = norm_d[rw];
                float o0 = acc0[r] * nd + bcol[0];
                float o1 = acc1[r] * nd + bcol[1];
                if (LAYER0) {
                    o0 = o0 * s[0] + sh[0];
                    o1 = o1 * s[1] + sh[1];
                    o0 = o0 > 0.f ? o0 : LEAKY * o0;
                    o1 = o1 > 0.f ? o1 : LEAKY * o1;
                    float ns = norm_s[rw];
                    o0 *= ns; o1 *= ns;
                    outb[(size_t)rw * D + col[0]] = (unsigned short)f2bf(o0);
                    outb[(size_t)rw * D + col[1]] = (unsigned short)f2bf(o1);
                } else {
                    outf[(size_t)rw * D + col[0]] = o0;
                    outf[(size_t)rw * D + col[1]] = o1;
                }
            }
        }
    }
}

// ---------------- launch ----------------

extern "C" void kernel_launch(void* const* d_in, const int* in_sizes, int n_in,
                              void* d_out, int out_size, void* d_ws, size_t ws_size,
                              hipStream_t stream) {
    const float* x     = (const float*)d_in[0];
    const int*   src   = (const int*)d_in[1];
    const int*   dst   = (const int*)d_in[2];
    const float* W1    = (const float*)d_in[3];
    const float* b1    = (const float*)d_in[4];
    const float* W2    = (const float*)d_in[5];
    const float* b2    = (const float*)d_in[6];
    const float* gamma = (const float*)d_in[7];
    const float* beta  = (const float*)d_in[8];
    const float* rmean = (const float*)d_in[9];
    const float* rvar  = (const float*)d_in[10];
    float* out = (float*)d_out;

    // bf16 gather-source scratch lives in d_out's first half (dead until the
    // final GEMM overwrites all of d_out with fp32 results).
    unsigned* hb = (unsigned*)d_out;                    // NN*64 u32 = 25.6 MB

    // ws layout (4B units)
    unsigned* Ahi   = (unsigned*)d_ws;                  // NN*64 u32 (bf16 hi pairs)
    unsigned* Alo   = Ahi + (size_t)NN * 64;            // NN*64 u32 (bf16 lo pairs)
    float*    norm  = (float*)(Alo + (size_t)NN * 64);  // 2N f32
    int*      deg   = (int*)(norm + 2 * NN);            // N int (unused this round)
    int*      hist  = deg + NN;                         // B*G int; row[] aliases after scanC
    int*      offs  = hist + B * G;                     // B*G int
    int*      bsum  = offs + B * G;                     // B int
    int*      boffs = bsum + B;                         // B int
    unsigned* ebuf  = (unsigned*)(boffs + B);           // NE u32
    float* norm_s = norm;
    float* norm_d = norm + NN;
    int*   row    = hist;                // aliases hist (dead after scanC)

    // per-XCD out-degree partials alias Ahi (dead until csr_agg writes it,
    // which happens after conv_kernel has consumed the reduction)
    int* degP = (int*)Ahi;                              // 8 * NN int = 3.2 MB

    hipMemsetAsync(degP, 0, (size_t)NXCD * NN * sizeof(int), stream);

    // counting sort by dst bucket (+ fused L2-local out-degree), local sort -> CSR
    hist_kernel<<<G, 1024, 0, stream>>>(src, dst, degP, hist);
    scanA<<<B * G / 256, 256, 0, stream>>>(hist, bsum);
    scanB<<<1, 64, 0, stream>>>(bsum, boffs);
    scanC<<<B * G / 256, 256, 0, stream>>>(hist, boffs, offs);
    sort_kernel<<<G, 1024, 0, stream>>>(src, dst, offs, ebuf);
    conv_kernel<<<(NN * 64 + 255) / 256, 256, 0, stream>>>(x, degP, norm_s, hb);
    local_sort<<<B, 256, 0, stream>>>(offs, ebuf, row, norm_d);

    const int AGG_BLOCKS = (NN + 3) / 4;
    const int GEMM_BLOCKS = 784;
    // layer 0: agg = selfloop + sum_e xs[src]  -> split bf16 hi/lo
    csr_agg<<<AGG_BLOCKS, 256, 0, stream>>>(row, (const int*)ebuf, hb, Ahi, Alo);
    gemm_kernel<true><<<GEMM_BLOCKS, 256, 0, stream>>>(Ahi, Alo, W1, b1,
                                                       norm_s, norm_d,
                                                       gamma, beta, rmean, rvar,
                                                       nullptr, (unsigned short*)hb);
    // layer 1: gather source = bf16 hs (norm_src folded)
    csr_agg<<<AGG_BLOCKS, 256, 0, stream>>>(row, (const int*)ebuf, hb, Ahi, Alo);
    gemm_kernel<false><<<GEMM_BLOCKS, 256, 0, stream>>>(Ahi, Alo, W2, b2,
                                                        norm_s, norm_d,
                                                        nullptr, nullptr, nullptr, nullptr,
                                                        out, nullptr);
}